// Round 9
// baseline (87.554 us; speedup 1.0000x reference)
//
#include <hip/hip_runtime.h>
#include <hip/hip_bf16.h>

typedef __attribute__((ext_vector_type(8))) short short8;
typedef __attribute__((ext_vector_type(4))) float floatx4;

#define BB 256
#define SS 512
#define VOCAB 50000
#define EMB_D 300
#define POS_MAX 512
#define POS_D 16
#define CNN_OUT 50
#define KW 5
#define NCLASS 10
#define C_IN 332            // EMB_D + 2*POS_D
#define NKS 55              // K-steps: 5 windows x 11
#define MROWS 32            // output positions per tile
#define TILES 8             // tiles per block (pipelined)
#define FROWS 36            // 32 outputs + 2+2 halo
#define FSTR 392            // LDS row stride in bf16 (784B)
#define E2STR 320           // bf16 E row stride: 640 B = 5 x 128B lines
#define NCH 38              // uint4 chunks per staged row (elems 0..303, write-clipped)
#define NEV (FROWS * NCH)   // 1368 flat E-copy slots
#define NWF (NKS * 4 * 64 * 8)   // 112640 packed B elems

__device__ __forceinline__ unsigned pack2bf(float x, float y) {
    __hip_bfloat162 h = __float22bfloat162_rn(make_float2(x, y));   // v_cvt_pk_bf16_f32
    return *reinterpret_cast<unsigned*>(&h);
}

__device__ __forceinline__ unsigned short f2bf(float x) {
    unsigned u = __float_as_uint(x);
    u += 0x7FFF + ((u >> 16) & 1);      // RNE (k_prep only)
    return (unsigned short)(u >> 16);
}

// ---------------- K-1: E fp32 -> E2 bf16 (stride 320) + rowz (pad mask) ----------------
__global__ __launch_bounds__(256) void k_cvt(const float* __restrict__ E,
                                             unsigned short* __restrict__ E2,
                                             int* __restrict__ rowz) {
    int row = blockIdx.x * 4 + (threadIdx.x >> 6);
    if (row >= VOCAB) return;
    int lane = threadIdx.x & 63;
    const float4* src = (const float4*)(E + (size_t)row * EMB_D);
    unsigned short* dst = E2 + (size_t)row * E2STR;
    float4 a = src[lane];                                   // elems 4L..4L+3
    unsigned nzb = __float_as_uint(a.x) | __float_as_uint(a.y) |
                   __float_as_uint(a.z) | __float_as_uint(a.w);
    *(uint2*)&dst[lane * 4] = make_uint2(pack2bf(a.x, a.y), pack2bf(a.z, a.w));
    if (lane < 11) {
        float4 bq = src[64 + lane];                         // elems 256..299
        nzb |= __float_as_uint(bq.x) | __float_as_uint(bq.y) |
               __float_as_uint(bq.z) | __float_as_uint(bq.w);
        *(uint2*)&dst[256 + lane * 4] = make_uint2(pack2bf(bq.x, bq.y), pack2bf(bq.z, bq.w));
    } else if (lane < 16) {
        *(uint2*)&dst[300 + (lane - 11) * 4] = make_uint2(0u, 0u);   // pad 300..319
    }
    bool nz = (nzb & 0x7FFFFFFFu) != 0u;    // -0.0 counts as zero (matches jnp ==0.0)
    unsigned long long bal = __ballot(nz);
    if (lane == 0) rowz[row] = (bal == 0ULL) ? 1 : 0;
}

// ---------------- K0: pack conv_w -> Wf (im2col B-fragment-linear bf16), zero ymax -------
__global__ __launch_bounds__(256) void k_prep(const float* __restrict__ conv_w,
                                              unsigned short* __restrict__ Wf,
                                              float* __restrict__ ymax) {
    int idx = blockIdx.x * 256 + threadIdx.x;
    if (idx < NWF) {
        int j = idx & 7, l = (idx >> 3) & 63, nb = (idx >> 9) & 3, ks = idx >> 11;
        int k = ks / 11;
        int c = (ks % 11) * 32 + ((l >> 4) << 3) + j;
        int col = nb * 16 + (l & 15);
        float v = 0.f;
        if (c < C_IN && col < CNN_OUT)
            v = conv_w[col * (C_IN * KW) + c * KW + k];
        Wf[idx] = f2bf(v);
    } else if (idx < NWF + BB * CNN_OUT) {
        ymax[idx - NWF] = 0.f;   // relu >= 0, so 0 is the identity for the max
    }
}

// ---------------- K1: nearest-entity distances ----------------
__global__ __launch_bounds__(512) void k_dist(const int* __restrict__ tokens,
                                              const int* __restrict__ e1p,
                                              const int* __restrict__ e2p,
                                              int* __restrict__ d1,
                                              int* __restrict__ d2) {
    __shared__ int cnt1, cnt2;
    __shared__ int lst1[SS], lst2[SS];
    int b = blockIdx.x, s = threadIdx.x;
    if (s == 0) { cnt1 = 0; cnt2 = 0; }
    __syncthreads();
    int tok = tokens[b * SS + s];
    int e1 = *e1p, e2 = *e2p;
    if (tok == e1) lst1[atomicAdd(&cnt1, 1)] = s;
    if (tok == e2) lst2[atomicAdd(&cnt2, 1)] = s;
    __syncthreads();
    int dd1 = POS_MAX - 1;
    int n1 = cnt1;
    for (int i = 0; i < n1; ++i) dd1 = min(dd1, abs(s - lst1[i]));
    int dd2 = POS_MAX - 1;
    int n2 = cnt2;
    for (int i = 0; i < n2; ++i) dd2 = min(dd2, abs(s - lst2[i]));
    d1[b * SS + s] = dd1;
    d2[b * SS + s] = dd2;
}

// ---------------- K2: fused im2col conv + relu + maxpool (pipelined tiles) ----------------
// Block: 256 thr = 4 waves; processes TILES=8 consecutive 32-row tiles of half a sentence.
// Double-buffered LDS (2 x 28.2 KB): while tile t runs MFMA+reduction, tile t+1's gather
// loads are in flight (issue-early / commit-late). rowz precomputed -> no ballot chain.
// MFMA: waves split K (14/14/14/13 of 55); 2-deep B prefetch. Reduction scratches cur
// (fully restaged next use). maxpool accumulated in-register across tiles; 1 atomic/block.
__global__ __launch_bounds__(256, 2) void k_fused(const int* __restrict__ tokens,
                                                  const int* __restrict__ d1,
                                                  const int* __restrict__ d2,
                                                  const int* __restrict__ rowz,
                                                  const unsigned short* __restrict__ E2,
                                                  const float* __restrict__ pos,
                                                  const unsigned short* __restrict__ Wf,
                                                  const float* __restrict__ conv_b,
                                                  float* __restrict__ ymax) {
    __shared__ __align__(16) short Fbuf[2][FROWS * FSTR];   // 2 x 28,224 B
    int tid = threadIdx.x, lane = tid & 63, w = tid >> 6;
    int b = blockIdx.x >> 1, half = blockIdx.x & 1;
    int base = half * (MROWS * TILES);

    const int* trow = tokens + b * SS;
    const int* d1r = d1 + b * SS;
    const int* d2r = d2 + b * SS;

    short* cur = Fbuf[0];
    short* nxt = Fbuf[1];

    // stage registers (held across the MFMA phase)
    uint4 ev[6];
    float4 pv[2];
    float pmsk[2];

    auto issue = [&](int srow) {
        #pragma unroll
        for (int j = 0; j < 6; ++j) {
            int idx = tid + j * 256;
            ev[j] = make_uint4(0u, 0u, 0u, 0u);
            if (idx < NEV) {
                int row = idx / NCH, ch = idx % NCH;
                int sp = srow - 2 + row;
                bool valid = (sp >= 0 && sp < SS);
                if (valid) {
                    int t = trow[sp];
                    ev[j] = ((const uint4*)(E2 + (size_t)t * E2STR))[ch];
                }
            }
        }
        #pragma unroll
        for (int j = 0; j < 2; ++j) {
            int idx = tid + j * 256;
            pv[j] = make_float4(0.f, 0.f, 0.f, 0.f);
            pmsk[j] = 0.f;
            if (idx < FROWS * 8) {
                int row = idx >> 3, q = idx & 7;
                int sp = srow - 2 + row;
                bool valid = (sp >= 0 && sp < SS);
                int table = q >> 2, i = q & 3;
                if (valid) {
                    int t = trow[sp];
                    int rz = rowz[t];                       // independent of dd chain
                    int dd = table ? d2r[sp] : d1r[sp];
                    pmsk[j] = rz ? 0.f : 1.f;
                    pv[j] = ((const float4*)(pos + dd * POS_D))[i];
                }
            }
        }
    };

    auto commit = [&](short* Fb) {
        #pragma unroll
        for (int j = 0; j < 6; ++j) {
            int idx = tid + j * 256;
            if (idx < NEV) {
                int row = idx / NCH, ch = idx % NCH;
                if (ch <= 36)
                    *(uint4*)&Fb[row * FSTR + ch * 8] = ev[j];
                else                                         // ch == 37: elems 296..299 only
                    *(uint2*)&Fb[row * FSTR + 296] = make_uint2(ev[j].x, ev[j].y);
            }
        }
        #pragma unroll
        for (int j = 0; j < 2; ++j) {
            int idx = tid + j * 256;
            if (idx < FROWS * 8) {
                int row = idx >> 3, q = idx & 7;
                int table = q >> 2, i = q & 3;
                float mk = pmsk[j];
                *(uint2*)&Fb[row * FSTR + EMB_D + table * POS_D + i * 4] =
                    make_uint2(pack2bf(pv[j].x * mk, pv[j].y * mk),
                               pack2bf(pv[j].z * mk, pv[j].w * mk));
            }
        }
        // zero K-pad cols 332..351 (rewritten every tile: reduction scratches them)
        #pragma unroll
        for (int j = 0; j < 2; ++j) {
            int idx = tid + j * 256;
            if (idx < FROWS * 10) {
                int row = idx / 10, dw = idx % 10;
                *(unsigned*)&Fb[row * FSTR + C_IN + dw * 2] = 0u;
            }
        }
    };

    // ---- prologue: stage tile 0 ----
    issue(base);
    commit(cur);
    __syncthreads();

    int arow = lane & 15, achunk = (lane >> 4) * 8;
    const short8* Bp = (const short8*)Wf;
    int lo = w * 14;
    int hi = min(lo + 14, NKS);
    float m = -1e30f;

    for (int ti = 0; ti < TILES; ++ti) {
        if (ti + 1 < TILES) issue(base + (ti + 1) * MROWS);   // loads fly under MFMA+red

        // ---- MFMA from cur: wave w does its K-steps, 2 m-frags x 4 n-frags ----
        floatx4 acc[2][4];
        #pragma unroll
        for (int mm = 0; mm < 2; ++mm)
            #pragma unroll
            for (int nn = 0; nn < 4; ++nn) acc[mm][nn] = (floatx4)0.f;

        short8 bA[4], bB[4];
        #pragma unroll
        for (int nb = 0; nb < 4; ++nb)
            bA[nb] = Bp[(lo * 4 + nb) * 64 + lane];
        if (lo + 1 < hi) {
            #pragma unroll
            for (int nb = 0; nb < 4; ++nb)
                bB[nb] = Bp[((lo + 1) * 4 + nb) * 64 + lane];
        }

        auto step = [&](int ks, short8 (&bf)[4], int pfks) {
            int k = ks / 11, kc = ks % 11;
            const short* abase = &cur[(arow + k) * FSTR + kc * 32 + achunk];
            #pragma unroll
            for (int mm = 0; mm < 2; ++mm) {
                short8 afrag = *(const short8*)(abase + mm * 16 * FSTR);
                #pragma unroll
                for (int nn = 0; nn < 4; ++nn)
                    acc[mm][nn] = __builtin_amdgcn_mfma_f32_16x16x32_bf16(afrag, bf[nn], acc[mm][nn], 0, 0, 0);
            }
            if (pfks < hi) {
                #pragma unroll
                for (int nb = 0; nb < 4; ++nb)
                    bf[nb] = Bp[(pfks * 4 + nb) * 64 + lane];
            }
        };

        int ks = lo;
        for (; ks + 1 < hi; ks += 2) {
            step(ks, bA, ks + 2);
            step(ks + 1, bB, ks + 3);
        }
        if (ks < hi) step(ks, bA, NKS);

        // ---- cross-wave reduction (scratch = cur; restaged before next use) ----
        __syncthreads();                  // all A-reads of cur done
        float* R = (float*)cur;
        #pragma unroll
        for (int round = 0; round < 2; ++round) {
            #pragma unroll
            for (int nn = 0; nn < 4; ++nn)
                *(floatx4*)&R[((w * 4 + nn) * 64 + lane) * 4] = acc[round][nn];
            __syncthreads();
            floatx4 t0 = *(floatx4*)&R[((0 * 4 + w) * 64 + lane) * 4];
            floatx4 t1 = *(floatx4*)&R[((1 * 4 + w) * 64 + lane) * 4];
            floatx4 t2 = *(floatx4*)&R[((2 * 4 + w) * 64 + lane) * 4];
            floatx4 t3 = *(floatx4*)&R[((3 * 4 + w) * 64 + lane) * 4];
            floatx4 red = (t0 + t1) + (t2 + t3);
            #pragma unroll
            for (int rg = 0; rg < 4; ++rg) m = fmaxf(m, red[rg]);
            if (round == 0) __syncthreads();   // region reused by round 1 writes
        }

        if (ti + 1 < TILES) commit(nxt);
        __syncthreads();                  // nxt staged; cur scratch reads done
        short* tmp = cur; cur = nxt; nxt = tmp;
    }

    // ---- epilogue: bias + relu + atomicMax (wave w owns cols w*16..w*16+15) ----
    int col = w * 16 + (lane & 15);
    float bias = (col < CNN_OUT) ? conv_b[col] : 0.f;
    m = fmaxf(m + bias, 0.f);             // relu floor
    m = fmaxf(m, __shfl_xor(m, 16));
    m = fmaxf(m, __shfl_xor(m, 32));
    if ((lane >> 4) == 0 && col < CNN_OUT)
        atomicMax((int*)ymax + b * CNN_OUT + col, __float_as_int(m));
}

// ---------------- K4: FC ----------------
__global__ __launch_bounds__(64) void k_fc(const float* __restrict__ ymax,
                                           const float* __restrict__ fc_w,
                                           const float* __restrict__ fc_b,
                                           float* __restrict__ out) {
    int b = blockIdx.x, n = threadIdx.x;
    if (n < NCLASS) {
        float a = fc_b[n];
        #pragma unroll
        for (int o = 0; o < CNN_OUT; ++o)
            a += ymax[b * CNN_OUT + o] * fc_w[n * CNN_OUT + o];
        out[b * NCLASS + n] = a;
    }
}

extern "C" void kernel_launch(void* const* d_in, const int* in_sizes, int n_in,
                              void* d_out, int out_size, void* d_ws, size_t ws_size,
                              hipStream_t stream) {
    const int*   tokens  = (const int*)  d_in[0];
    const float* embed   = (const float*)d_in[1];
    const float* pos     = (const float*)d_in[2];
    const float* conv_w  = (const float*)d_in[3];
    const float* conv_b  = (const float*)d_in[4];
    const float* fc_w    = (const float*)d_in[5];
    const float* fc_b    = (const float*)d_in[6];
    const int*   e1p     = (const int*)  d_in[7];
    const int*   e2p     = (const int*)  d_in[8];
    float* out = (float*)d_out;

    char* ws = (char*)d_ws;
    size_t off = 0;
    unsigned short* E2 = (unsigned short*)(ws + off); off += (size_t)VOCAB * E2STR * 2; // 32,000,000
    unsigned short* Wf = (unsigned short*)(ws + off); off += (size_t)NWF * 2;           // 225,280
    int*   d1     = (int*)  (ws + off); off += (size_t)BB * SS * 4;
    int*   d2     = (int*)  (ws + off); off += (size_t)BB * SS * 4;
    int*   rowzp  = (int*)  (ws + off); off += (size_t)VOCAB * 4;
    float* ymax   = (float*)(ws + off); off += (size_t)BB * CNN_OUT * 4;
    (void)ws_size; (void)in_sizes; (void)n_in; (void)out_size;

    // K-1: E -> bf16 + rowz (streaming roofline)
    hipLaunchKernelGGL(k_cvt, dim3((VOCAB + 3) / 4), dim3(256), 0, stream, embed, E2, rowzp);
    // K0: weight pack + ymax zero-init (every launch: atomicMax state must reset)
    {
        int total = NWF + BB * CNN_OUT;
        hipLaunchKernelGGL(k_prep, dim3((total + 255) / 256), dim3(256), 0, stream,
                           conv_w, Wf, ymax);
    }
    // K1: distances
    hipLaunchKernelGGL(k_dist, dim3(BB), dim3(512), 0, stream, tokens, e1p, e2p, d1, d2);
    // K2: pipelined fused conv (8 tiles/block, double-buffered LDS, 2 blocks/CU)
    hipLaunchKernelGGL(k_fused, dim3(BB * (SS / (MROWS * TILES))), dim3(256), 0, stream,
                       tokens, d1, d2, rowzp, E2, pos, Wf, conv_b, ymax);
    // K4: FC
    hipLaunchKernelGGL(k_fc, dim3(BB), dim3(64), 0, stream, ymax, fc_w, fc_b, out);
}

// Round 10
// 68.395 us; speedup vs baseline: 1.2801x; 1.2801x over previous
//
#include <hip/hip_runtime.h>
#include <hip/hip_bf16.h>

typedef __attribute__((ext_vector_type(8))) short short8;
typedef __attribute__((ext_vector_type(4))) float floatx4;

#define BB 256
#define SS 512
#define VOCAB 50000
#define EMB_D 300
#define POS_MAX 512
#define POS_D 16
#define CNN_OUT 50
#define KW 5
#define NCLASS 10
#define C_IN 332            // EMB_D + 2*POS_D
#define NKS 55              // K-steps: 5 windows x 11
#define MROWS 64            // output positions per block
#define FROWS 68            // 64 outputs + 2+2 halo
#define FSTR 392            // LDS row stride in bf16 (784B: stride%128B=16 -> 2-way max on A-reads)
#define E2STR 320           // bf16 E row stride: 640 B = 5 x 128B lines
#define NWF (NKS * 4 * 64 * 8)   // 112640 packed B elems
#define NEV (FROWS * 37)    // 2516 uint4 E-copy slots (elems 0..295)
#define NB_CVT 6250         // 50000/8 rows
#define NB_PREP 245         // (112640+12800)/512
#define NB_DIST BB

__device__ __forceinline__ unsigned pack2bf(float x, float y) {
    __hip_bfloat162 h = __float22bfloat162_rn(make_float2(x, y));   // v_cvt_pk_bf16_f32
    return *reinterpret_cast<unsigned*>(&h);
}

__device__ __forceinline__ unsigned short f2bf(float x) {
    unsigned u = __float_as_uint(x);
    u += 0x7FFF + ((u >> 16) & 1);      // RNE (prep role only)
    return (unsigned short)(u >> 16);
}

// ---------------- K0: merged prep: E->bf16+rowz | Wf pack + ymax zero | distances -------
__global__ __launch_bounds__(512) void k_pre(const float* __restrict__ E,
                                             unsigned short* __restrict__ E2,
                                             int* __restrict__ rowz,
                                             const float* __restrict__ conv_w,
                                             unsigned short* __restrict__ Wf,
                                             float* __restrict__ ymax,
                                             const int* __restrict__ tokens,
                                             const int* __restrict__ e1p,
                                             const int* __restrict__ e2p,
                                             int* __restrict__ d1,
                                             int* __restrict__ d2) {
    __shared__ int cnt1, cnt2;
    __shared__ int lst1[SS], lst2[SS];
    int bid = blockIdx.x, tid = threadIdx.x;
    if (bid < NB_CVT) {
        // ---- cvt: 8 vocab rows per block ----
        int row = bid * 8 + (tid >> 6);
        int lane = tid & 63;
        const float4* src = (const float4*)(E + (size_t)row * EMB_D);
        unsigned short* dst = E2 + (size_t)row * E2STR;
        float4 a = src[lane];                                   // elems 4L..4L+3
        unsigned nzb = __float_as_uint(a.x) | __float_as_uint(a.y) |
                       __float_as_uint(a.z) | __float_as_uint(a.w);
        *(uint2*)&dst[lane * 4] = make_uint2(pack2bf(a.x, a.y), pack2bf(a.z, a.w));
        if (lane < 11) {
            float4 bq = src[64 + lane];                         // elems 256..299
            nzb |= __float_as_uint(bq.x) | __float_as_uint(bq.y) |
                   __float_as_uint(bq.z) | __float_as_uint(bq.w);
            *(uint2*)&dst[256 + lane * 4] = make_uint2(pack2bf(bq.x, bq.y), pack2bf(bq.z, bq.w));
        } else if (lane < 16) {
            *(uint2*)&dst[300 + (lane - 11) * 4] = make_uint2(0u, 0u);   // pad 300..319
        }
        bool nz = (nzb & 0x7FFFFFFFu) != 0u;    // -0.0 counts as zero
        unsigned long long bal = __ballot(nz);
        unsigned my = (unsigned)(bal >> ((tid >> 6) * 64)) ;    // (shift within same wave: bal is per-wave)
        (void)my;
        if (lane == 0) rowz[row] = (bal == 0ULL) ? 1 : 0;
    } else if (bid < NB_CVT + NB_PREP) {
        // ---- prep: Wf pack + ymax zero ----
        int idx = (bid - NB_CVT) * 512 + tid;
        if (idx < NWF) {
            int j = idx & 7, l = (idx >> 3) & 63, nb = (idx >> 9) & 3, ks = idx >> 11;
            int k = ks / 11;
            int c = (ks % 11) * 32 + ((l >> 4) << 3) + j;
            int col = nb * 16 + (l & 15);
            float v = 0.f;
            if (c < C_IN && col < CNN_OUT)
                v = conv_w[col * (C_IN * KW) + c * KW + k];
            Wf[idx] = f2bf(v);
        } else if (idx < NWF + BB * CNN_OUT) {
            ymax[idx - NWF] = 0.f;   // relu >= 0: 0 is identity for the max
        }
    } else {
        // ---- distances: one sentence per block ----
        int b = bid - NB_CVT - NB_PREP;
        int s = tid;
        if (s == 0) { cnt1 = 0; cnt2 = 0; }
        __syncthreads();
        int tok = tokens[b * SS + s];
        int e1 = *e1p, e2 = *e2p;
        if (tok == e1) lst1[atomicAdd(&cnt1, 1)] = s;
        if (tok == e2) lst2[atomicAdd(&cnt2, 1)] = s;
        __syncthreads();
        int dd1 = POS_MAX - 1;
        int n1 = cnt1;
        for (int i = 0; i < n1; ++i) dd1 = min(dd1, abs(s - lst1[i]));
        int dd2 = POS_MAX - 1;
        int n2 = cnt2;
        for (int i = 0; i < n2; ++i) dd2 = min(dd2, abs(s - lst2[i]));
        d1[b * SS + s] = dd1;
        d2[b * SS + s] = dd2;
    }
}

// ---------------- K2: fused im2col conv + relu + maxpool (8 waves, 2D K x M split) ------
// Block: 512 thr = 8 waves; tile = 64 output positions x 64 cols (50 valid).
// Wave w: kw=w>>1 owns K-quarter [kw*14, min(+14,55)), mw=w&1 owns 32-row half; acc[2][4].
// 16 waves/CU resident (2 blocks): gather latency hidden by TLP, not in-block pipelining.
// Reduction: 2 rounds (mm) of 32KB: slot s=mw*4+nn, 4 kw-sources; wave w sums slot s=w.
__global__ __launch_bounds__(512, 4) void k_fused(const int* __restrict__ tokens,
                                                  const int* __restrict__ d1,
                                                  const int* __restrict__ d2,
                                                  const int* __restrict__ rowz,
                                                  const unsigned short* __restrict__ E2,
                                                  const float* __restrict__ pos,
                                                  const unsigned short* __restrict__ Wf,
                                                  const float* __restrict__ conv_b,
                                                  float* __restrict__ ymax) {
    __shared__ __align__(16) short F[FROWS * FSTR];   // 53,312 B
    int tid = threadIdx.x, lane = tid & 63, w = tid >> 6;
    int b = blockIdx.x >> 3, sb = blockIdx.x & 7;
    int s0 = sb * MROWS;

    const int* trow = tokens + b * SS;
    const int* d1r = d1 + b * SS;
    const int* d2r = d2 + b * SS;

    // ---- stage: phase 1 — issue everything (5 E-chunks + tail + pos per thread) ----
    uint4 ev[5];
    #pragma unroll
    for (int j = 0; j < 5; ++j) {
        int idx = tid + j * 512;
        ev[j] = make_uint4(0u, 0u, 0u, 0u);
        if (idx < NEV) {
            int row = idx / 37, ch = idx % 37;
            int sp = s0 - 2 + row;
            if (sp >= 0 && sp < SS) {
                int t = trow[sp];
                ev[j] = ((const uint4*)(E2 + (size_t)t * E2STR))[ch];
            }
        }
    }
    uint2 et = make_uint2(0u, 0u);                      // elems 296..299
    if (tid < FROWS) {
        int sp = s0 - 2 + tid;
        if (sp >= 0 && sp < SS) {
            int t = trow[sp];
            et = *(const uint2*)&E2[(size_t)t * E2STR + 296];
        }
    }
    float4 pq[2];                                        // half a pos row (8 floats)
    float mk = 0.f;
    if (tid < FROWS * 4) {                               // (row, table, half)
        int row = tid >> 2, tb = (tid >> 1) & 1, hf = tid & 1;
        int sp = s0 - 2 + row;
        if (sp >= 0 && sp < SS) {
            int t = trow[sp];
            int rz = rowz[t];
            int dd = tb ? d2r[sp] : d1r[sp];
            mk = rz ? 0.f : 1.f;
            const float4* ps = (const float4*)(pos + dd * POS_D);
            pq[0] = ps[hf * 2 + 0];
            pq[1] = ps[hf * 2 + 1];
        } else { pq[0] = pq[1] = make_float4(0.f, 0.f, 0.f, 0.f); }
    } else { pq[0] = pq[1] = make_float4(0.f, 0.f, 0.f, 0.f); }

    // ---- stage: phase 2 — commit to LDS ----
    #pragma unroll
    for (int j = 0; j < 5; ++j) {
        int idx = tid + j * 512;
        if (idx < NEV) {
            int row = idx / 37, ch = idx % 37;
            *(uint4*)&F[row * FSTR + ch * 8] = ev[j];
        }
    }
    if (tid < FROWS)
        *(uint2*)&F[tid * FSTR + 296] = et;
    if (tid < FROWS * 4) {
        int row = tid >> 2, tb = (tid >> 1) & 1, hf = tid & 1;
        int cb = EMB_D + tb * POS_D + hf * 8;
        *(uint2*)&F[row * FSTR + cb] =
            make_uint2(pack2bf(pq[0].x * mk, pq[0].y * mk), pack2bf(pq[0].z * mk, pq[0].w * mk));
        *(uint2*)&F[row * FSTR + cb + 4] =
            make_uint2(pack2bf(pq[1].x * mk, pq[1].y * mk), pack2bf(pq[1].z * mk, pq[1].w * mk));
    }
    {   // zero K-pad cols 332..351 (10 dwords x 68 rows = 680 slots)
        #pragma unroll
        for (int j = 0; j < 2; ++j) {
            int idx = tid + j * 512;
            if (idx < FROWS * 10) {
                int row = idx / 10, dw = idx % 10;
                *(unsigned*)&F[row * FSTR + C_IN + dw * 2] = 0u;
            }
        }
    }
    __syncthreads();

    // ---- MFMA: wave (kw, mw): K-steps [kw*14, min(+14,55)), rows mw*32..+31 ----
    int kw = w >> 1, mw = w & 1;
    floatx4 acc[2][4];
    #pragma unroll
    for (int mm = 0; mm < 2; ++mm)
        #pragma unroll
        for (int nn = 0; nn < 4; ++nn) acc[mm][nn] = (floatx4)0.f;

    int arow = lane & 15, achunk = (lane >> 4) * 8;
    const short8* Bp = (const short8*)Wf;
    int lo = kw * 14;
    int hi = min(lo + 14, NKS);

    short8 bA[4], bB[4];
    #pragma unroll
    for (int nb = 0; nb < 4; ++nb)
        bA[nb] = Bp[(lo * 4 + nb) * 64 + lane];
    #pragma unroll
    for (int nb = 0; nb < 4; ++nb)
        bB[nb] = Bp[((lo + 1) * 4 + nb) * 64 + lane];

    auto step = [&](int ks, short8 (&bf)[4], int pfks) {
        int k = ks / 11, kc = ks % 11;
        const short* abase = &F[(mw * 32 + arow + k) * FSTR + kc * 32 + achunk];
        #pragma unroll
        for (int mm = 0; mm < 2; ++mm) {
            short8 afrag = *(const short8*)(abase + mm * 16 * FSTR);
            #pragma unroll
            for (int nn = 0; nn < 4; ++nn)
                acc[mm][nn] = __builtin_amdgcn_mfma_f32_16x16x32_bf16(afrag, bf[nn], acc[mm][nn], 0, 0, 0);
        }
        if (pfks < hi) {
            #pragma unroll
            for (int nb = 0; nb < 4; ++nb)
                bf[nb] = Bp[(pfks * 4 + nb) * 64 + lane];
        }
    };

    int ks = lo;
    for (; ks + 1 < hi; ks += 2) {
        step(ks, bA, ks + 2);
        step(ks + 1, bB, ks + 3);
    }
    if (ks < hi) step(ks, bA, NKS);   // tail

    // ---- cross-wave reduction: 2 rounds (mm) of 32KB through F ----
    __syncthreads();                  // all F A-reads done; scratch = F bytes 0..32767
    float* R = (float*)F;
    float m = -1e30f;
    #pragma unroll
    for (int mm = 0; mm < 2; ++mm) {
        #pragma unroll
        for (int nn = 0; nn < 4; ++nn)
            *(floatx4*)&R[(((mw * 4 + nn) * 4 + kw) * 64 + lane) * 4] = acc[mm][nn];
        __syncthreads();
        floatx4 t0 = *(floatx4*)&R[((w * 4 + 0) * 64 + lane) * 4];
        floatx4 t1 = *(floatx4*)&R[((w * 4 + 1) * 64 + lane) * 4];
        floatx4 t2 = *(floatx4*)&R[((w * 4 + 2) * 64 + lane) * 4];
        floatx4 t3 = *(floatx4*)&R[((w * 4 + 3) * 64 + lane) * 4];
        floatx4 red = (t0 + t1) + (t2 + t3);
        #pragma unroll
        for (int rg = 0; rg < 4; ++rg) m = fmaxf(m, red[rg]);
        if (mm == 0) __syncthreads();
    }

    // ---- epilogue: bias + relu + atomicMax (wave w owns cols (w&3)*16..+15) ----
    int col = (w & 3) * 16 + (lane & 15);
    float bias = (col < CNN_OUT) ? conv_b[col] : 0.f;
    m = fmaxf(m + bias, 0.f);             // relu floor
    m = fmaxf(m, __shfl_xor(m, 16));
    m = fmaxf(m, __shfl_xor(m, 32));
    if ((lane >> 4) == 0 && col < CNN_OUT)
        atomicMax((int*)ymax + b * CNN_OUT + col, __float_as_int(m));
}

// ---------------- K4: FC ----------------
__global__ __launch_bounds__(64) void k_fc(const float* __restrict__ ymax,
                                           const float* __restrict__ fc_w,
                                           const float* __restrict__ fc_b,
                                           float* __restrict__ out) {
    int b = blockIdx.x, n = threadIdx.x;
    if (n < NCLASS) {
        float a = fc_b[n];
        #pragma unroll
        for (int o = 0; o < CNN_OUT; ++o)
            a += ymax[b * CNN_OUT + o] * fc_w[n * CNN_OUT + o];
        out[b * NCLASS + n] = a;
    }
}

extern "C" void kernel_launch(void* const* d_in, const int* in_sizes, int n_in,
                              void* d_out, int out_size, void* d_ws, size_t ws_size,
                              hipStream_t stream) {
    const int*   tokens  = (const int*)  d_in[0];
    const float* embed   = (const float*)d_in[1];
    const float* pos     = (const float*)d_in[2];
    const float* conv_w  = (const float*)d_in[3];
    const float* conv_b  = (const float*)d_in[4];
    const float* fc_w    = (const float*)d_in[5];
    const float* fc_b    = (const float*)d_in[6];
    const int*   e1p     = (const int*)  d_in[7];
    const int*   e2p     = (const int*)  d_in[8];
    float* out = (float*)d_out;

    char* ws = (char*)d_ws;
    size_t off = 0;
    unsigned short* E2 = (unsigned short*)(ws + off); off += (size_t)VOCAB * E2STR * 2; // 32,000,000
    unsigned short* Wf = (unsigned short*)(ws + off); off += (size_t)NWF * 2;           // 225,280
    int*   d1     = (int*)  (ws + off); off += (size_t)BB * SS * 4;
    int*   d2     = (int*)  (ws + off); off += (size_t)BB * SS * 4;
    int*   rowzp  = (int*)  (ws + off); off += (size_t)VOCAB * 4;
    float* ymax   = (float*)(ws + off); off += (size_t)BB * CNN_OUT * 4;
    (void)ws_size; (void)in_sizes; (void)n_in; (void)out_size;

    // K0: merged prep (cvt | weight pack + ymax reset | distances) — one dispatch
    hipLaunchKernelGGL(k_pre, dim3(NB_CVT + NB_PREP + NB_DIST), dim3(512), 0, stream,
                       embed, E2, rowzp, conv_w, Wf, ymax, tokens, e1p, e2p, d1, d2);
    // K2: fused conv (64-row tiles, 8 waves, 16 waves/CU)
    hipLaunchKernelGGL(k_fused, dim3(BB * (SS / MROWS)), dim3(512), 0, stream,
                       tokens, d1, d2, rowzp, E2, pos, Wf, conv_b, ymax);
    // K4: FC
    hipLaunchKernelGGL(k_fc, dim3(BB), dim3(64), 0, stream, ymax, fc_w, fc_b, out);
}